// Round 1
// baseline (4676.578 us; speedup 1.0000x reference)
//
#include <hip/hip_runtime.h>
#include <cstdint>
#include <cstddef>

// BottomUpNet: N=8192 rows independent; K=16 sequential steps.
// Per step: Y1=[h1|m1]=relu(x@[OW1|MW1]+b), h2=relu(h1@OW2+Ob2) (fp32 out),
// m2=relu(m1@MW2+Mb2), summary=relu(m2@MW3+Mb3), pred=sigmoid(h2@OW3+Ob3),
// out *= pred.  All big GEMMs via fp16 hi/lo split (3 MFMAs) => ~fp32 accuracy.

typedef _Float16 half8 __attribute__((ext_vector_type(8)));
typedef float floatx4 __attribute__((ext_vector_type(4)));

__device__ __forceinline__ void gload16(const void* g, void* l) {
  // async global->LDS, 16B/lane, LDS dest = wave-uniform base + lane*16
  __builtin_amdgcn_global_load_lds(
      (__attribute__((address_space(1))) void*)const_cast<void*>(g),
      (__attribute__((address_space(3))) void*)l,
      16, 0, 0);
}

struct GArg {
  const _Float16* AH0; const _Float16* AL0;   // A region 0 (k < kcut)
  const _Float16* AH1; const _Float16* AL1;   // A region 1 (k >= kcut)
  const _Float16* BH;  const _Float16* BL;    // B transposed: [N][K]
  const float* bias;
  _Float16* CH; _Float16* CL;                 // hi/lo fp16 out (if Cf == null)
  float* Cf;                                  // fp32 out (if non-null)
};

// C = relu(A @ B^T + bias); A: M x Ktot (hi/lo fp16), B stored N x Ktot (hi/lo).
// Tile 128x128, BK=32, 256 threads (4 waves, each 64x64 = 4x4 MFMA tiles).
__global__ __launch_bounds__(256)
void gemm_split_kernel(GArg ga, GArg gb, int ldA0, int ldA1, int kcut, int Ktot, int ldC)
{
  __shared__ _Float16 sAh[128 * 32];
  __shared__ _Float16 sAl[128 * 32];
  __shared__ _Float16 sBh[128 * 32];
  __shared__ _Float16 sBl[128 * 32];

  const GArg g = (blockIdx.z == 0) ? ga : gb;

  const int tid  = threadIdx.x;
  const int lane = tid & 63;
  const int wave = tid >> 6;
  const int wm = (wave >> 1) * 64;   // wave row offset in tile
  const int wn = (wave & 1) * 64;    // wave col offset in tile

  const int mBase = blockIdx.x * 128;
  const int nBase = blockIdx.y * 128;

  // staging lane coords: 16 rows/chunk, 4 lanes/row (16B each)
  const int lr  = lane >> 2;
  const int lc8 = (lane & 3) * 8;

  // fragment lane coords
  const int fr = lane & 15;
  const int fq = lane >> 4;

  floatx4 acc[4][4];
#pragma unroll
  for (int i = 0; i < 4; ++i)
#pragma unroll
    for (int j = 0; j < 4; ++j)
      acc[i][j] = (floatx4)0.0f;

  for (int kt = 0; kt < Ktot; kt += 32) {
    const _Float16* aH; const _Float16* aL; int pA; int kl;
    if (kt < kcut) { aH = g.AH0; aL = g.AL0; pA = ldA0; kl = kt; }
    else           { aH = g.AH1; aL = g.AL1; pA = ldA1; kl = kt - kcut; }

#pragma unroll
    for (int cc = 0; cc < 2; ++cc) {
      const int c = wave * 2 + cc;            // chunk 0..7 (16 rows each)
      const int arow = mBase + c * 16 + lr;
      const int brow = nBase + c * 16 + lr;
      gload16(aH   + (size_t)arow * pA   + kl + lc8, &sAh[c * 512]);
      gload16(aL   + (size_t)arow * pA   + kl + lc8, &sAl[c * 512]);
      gload16(g.BH + (size_t)brow * Ktot + kt + lc8, &sBh[c * 512]);
      gload16(g.BL + (size_t)brow * Ktot + kt + lc8, &sBl[c * 512]);
    }
    __syncthreads();

    half8 ah[4], al[4], bh[4], bl[4];
#pragma unroll
    for (int i = 0; i < 4; ++i) {
      const int off = (wm + i * 16 + fr) * 32 + fq * 8;
      ah[i] = *(const half8*)&sAh[off];
      al[i] = *(const half8*)&sAl[off];
    }
#pragma unroll
    for (int j = 0; j < 4; ++j) {
      const int off = (wn + j * 16 + fr) * 32 + fq * 8;
      bh[j] = *(const half8*)&sBh[off];
      bl[j] = *(const half8*)&sBl[off];
    }
#pragma unroll
    for (int i = 0; i < 4; ++i)
#pragma unroll
      for (int j = 0; j < 4; ++j) {
        acc[i][j] = __builtin_amdgcn_mfma_f32_16x16x32_f16(al[i], bh[j], acc[i][j], 0, 0, 0);
        acc[i][j] = __builtin_amdgcn_mfma_f32_16x16x32_f16(ah[i], bl[j], acc[i][j], 0, 0, 0);
        acc[i][j] = __builtin_amdgcn_mfma_f32_16x16x32_f16(ah[i], bh[j], acc[i][j], 0, 0, 0);
      }
    __syncthreads();
  }

  // epilogue: bias + relu, store fp32 or hi/lo fp16
#pragma unroll
  for (int j = 0; j < 4; ++j) {
    const int col = nBase + wn + j * 16 + fr;
    const float bv = g.bias[col];
#pragma unroll
    for (int i = 0; i < 4; ++i) {
#pragma unroll
      for (int r = 0; r < 4; ++r) {
        const int row = mBase + wm + i * 16 + fq * 4 + r;
        float v = acc[i][j][r] + bv;
        v = fmaxf(v, 0.0f);
        const size_t idx = (size_t)row * ldC + col;
        if (g.Cf) {
          g.Cf[idx] = v;
        } else {
          const _Float16 h = (_Float16)v;
          g.CH[idx] = h;
          g.CL[idx] = (_Float16)(v - (float)h);
        }
      }
    }
  }
}

// W (K x N fp32, row-major) -> out (N x K fp16 hi/lo), i.e. transposed
__global__ void wconv_kernel(const float* __restrict__ W, int K, int N,
                             _Float16* __restrict__ oH, _Float16* __restrict__ oL) {
  int idx = blockIdx.x * 256 + threadIdx.x;   // idx = n*K + k (output-coalesced)
  if (idx >= K * N) return;
  int n = idx / K, k = idx - n * K;
  float v = W[(size_t)k * N + n];
  _Float16 h = (_Float16)v;
  oH[idx] = h;
  oL[idx] = (_Float16)(v - (float)h);
}

__global__ void bcat_kernel(const float* __restrict__ b0, const float* __restrict__ b1,
                            float* __restrict__ o) {
  int i = blockIdx.x * 256 + threadIdx.x;     // 2048 total
  o[i] = (i < 1024) ? b0[i] : b1[i - 1024];
}

__global__ void init_summary_kernel(const float* __restrict__ agg,
                                    _Float16* __restrict__ sH, _Float16* __restrict__ sL) {
  int idx = blockIdx.x * 256 + threadIdx.x;   // 8192*1024
  float v = agg[idx & 1023];
  _Float16 h = (_Float16)v;
  sH[idx] = h;
  sL[idx] = (_Float16)(v - (float)h);
}

__global__ void tow_slice_kernel(const float* __restrict__ towers, int k,
                                 _Float16* __restrict__ tH, _Float16* __restrict__ tL) {
  int idx = blockIdx.x * 256 + threadIdx.x;   // n*64 + f
  int n = idx >> 6, f = idx & 63;
  float v = towers[((size_t)n * 16 + k) * 64 + f];
  _Float16 h = (_Float16)v;
  tH[idx] = h;
  tL[idx] = (_Float16)(v - (float)h);
}

// pred = sigmoid(h2 @ OW3 + Ob3); out = (step==0) ? pred : out*pred
__global__ void gemv_pred_kernel(const float* __restrict__ h2, const float* __restrict__ w3,
                                 const float* __restrict__ b3, float* __restrict__ out, int step) {
  int row  = blockIdx.x * 4 + (threadIdx.x >> 6);
  int lane = threadIdx.x & 63;
  const float* hr = h2 + (size_t)row * 1024;
  float s = 0.0f;
#pragma unroll
  for (int j = 0; j < 1024; j += 64) s += hr[j + lane] * w3[j + lane];
#pragma unroll
  for (int off = 32; off > 0; off >>= 1) s += __shfl_down(s, off);
  if (lane == 0) {
    float p = 1.0f / (1.0f + expf(-(s + b3[0])));
    if (step == 0) out[row] = p;
    else           out[row] *= p;
  }
}

extern "C" void kernel_launch(void* const* d_in, const int* in_sizes, int n_in,
                              void* d_out, int out_size, void* d_ws, size_t ws_size,
                              hipStream_t stream) {
  const float* towers = (const float*)d_in[0];
  const float* agg    = (const float*)d_in[1];
  const float* MW1 = (const float*)d_in[2];
  const float* Mb1 = (const float*)d_in[3];
  const float* MW2 = (const float*)d_in[4];
  const float* Mb2 = (const float*)d_in[5];
  const float* MW3 = (const float*)d_in[6];
  const float* Mb3 = (const float*)d_in[7];
  const float* OW1 = (const float*)d_in[8];
  const float* Ob1 = (const float*)d_in[9];
  const float* OW2 = (const float*)d_in[10];
  const float* Ob2 = (const float*)d_in[11];
  const float* OW3 = (const float*)d_in[12];
  const float* Ob3 = (const float*)d_in[13];
  float* out = (float*)d_out;

  // ws layout (~183 MiB total)
  _Float16* p = (_Float16*)d_ws;
  _Float16* Wt1H = p; p += (size_t)2048 * 1088;
  _Float16* Wt1L = p; p += (size_t)2048 * 1088;
  _Float16* Wt2H = p; p += (size_t)2048 * 1024;   // [OW2^T ; MW2^T]
  _Float16* Wt2L = p; p += (size_t)2048 * 1024;
  _Float16* Wt3H = p; p += (size_t)1024 * 1024;
  _Float16* Wt3L = p; p += (size_t)1024 * 1024;
  _Float16* sumH = p; p += (size_t)8192 * 1024;
  _Float16* sumL = p; p += (size_t)8192 * 1024;
  _Float16* Y1H  = p; p += (size_t)8192 * 2048;   // [h1 | m1]
  _Float16* Y1L  = p; p += (size_t)8192 * 2048;
  _Float16* m2H  = p; p += (size_t)8192 * 1024;
  _Float16* m2L  = p; p += (size_t)8192 * 1024;
  _Float16* towH = p; p += (size_t)8192 * 64;
  _Float16* towL = p; p += (size_t)8192 * 64;
  float* h2f  = (float*)p; p += (size_t)8192 * 1024 * 2;
  float* b1ws = (float*)p; p += 4096;

  // per-call setup: convert weights (transposed, hi/lo), concat bias1, init summary
  {
    int tot = 1088 * 1024;
    wconv_kernel<<<dim3((tot + 255) / 256), dim3(256), 0, stream>>>(OW1, 1088, 1024, Wt1H, Wt1L);
    wconv_kernel<<<dim3((tot + 255) / 256), dim3(256), 0, stream>>>(MW1, 1088, 1024,
        Wt1H + (size_t)1024 * 1088, Wt1L + (size_t)1024 * 1088);
    tot = 1024 * 1024;
    wconv_kernel<<<dim3((tot + 255) / 256), dim3(256), 0, stream>>>(OW2, 1024, 1024, Wt2H, Wt2L);
    wconv_kernel<<<dim3((tot + 255) / 256), dim3(256), 0, stream>>>(MW2, 1024, 1024,
        Wt2H + (size_t)1024 * 1024, Wt2L + (size_t)1024 * 1024);
    wconv_kernel<<<dim3((tot + 255) / 256), dim3(256), 0, stream>>>(MW3, 1024, 1024, Wt3H, Wt3L);
    bcat_kernel<<<dim3(8), dim3(256), 0, stream>>>(Ob1, Mb1, b1ws);
    init_summary_kernel<<<dim3(32768), dim3(256), 0, stream>>>(agg, sumH, sumL);
  }

  for (int k = 0; k < 16; ++k) {
    tow_slice_kernel<<<dim3(2048), dim3(256), 0, stream>>>(towers, k, towH, towL);

    // K1: x=[summary | tower_k] (K=1088) @ Wt1 -> Y1=[h1|m1] (N=2048)
    GArg a1; a1.AH0 = sumH; a1.AL0 = sumL; a1.AH1 = towH; a1.AL1 = towL;
    a1.BH = Wt1H; a1.BL = Wt1L; a1.bias = b1ws; a1.CH = Y1H; a1.CL = Y1L; a1.Cf = nullptr;
    gemm_split_kernel<<<dim3(64, 16, 1), dim3(256), 0, stream>>>(a1, a1, 1024, 64, 1024, 1088, 2048);

    // K2 batched: z=0 h1@OW2 -> h2 (fp32); z=1 m1@MW2 -> m2 (hi/lo)
    GArg a2; a2.AH0 = Y1H; a2.AL0 = Y1L; a2.AH1 = Y1H; a2.AL1 = Y1L;
    a2.BH = Wt2H; a2.BL = Wt2L; a2.bias = Ob2; a2.CH = nullptr; a2.CL = nullptr; a2.Cf = h2f;
    GArg b2; b2.AH0 = Y1H + 1024; b2.AL0 = Y1L + 1024; b2.AH1 = Y1H + 1024; b2.AL1 = Y1L + 1024;
    b2.BH = Wt2H + (size_t)1024 * 1024; b2.BL = Wt2L + (size_t)1024 * 1024; b2.bias = Mb2;
    b2.CH = m2H; b2.CL = m2L; b2.Cf = nullptr;
    gemm_split_kernel<<<dim3(64, 8, 2), dim3(256), 0, stream>>>(a2, b2, 2048, 2048, 1024, 1024, 1024);

    // K3: m2 @ MW3 -> summary (in-place safe: K1 of this step already read summary)
    GArg a3; a3.AH0 = m2H; a3.AL0 = m2L; a3.AH1 = m2H; a3.AL1 = m2L;
    a3.BH = Wt3H; a3.BL = Wt3L; a3.bias = Mb3; a3.CH = sumH; a3.CL = sumL; a3.Cf = nullptr;
    gemm_split_kernel<<<dim3(64, 8, 1), dim3(256), 0, stream>>>(a3, a3, 1024, 1024, 1024, 1024, 1024);

    // K4: pred + product accumulate
    gemv_pred_kernel<<<dim3(2048), dim3(256), 0, stream>>>(h2f, OW3, Ob3, out, k);
  }
}

// Round 2
// 4444.043 us; speedup vs baseline: 1.0523x; 1.0523x over previous
//
#include <hip/hip_runtime.h>
#include <cstdint>
#include <cstddef>

// BottomUpNet: N=8192 rows independent; K=16 sequential steps.
// m-chain (summary recurrence): fp16 hi/lo split, 3 MFMAs => ~fp32 exact
// (errors would compound over 48 layers with fixed weights).
// h-chain (h1,h2 -> pred): plain fp16, 1 MFMA => per-pred rel err ~5e-4,
// non-compounding across steps; budget is 2% rel on prod of 16 preds.

typedef _Float16 half8 __attribute__((ext_vector_type(8)));
typedef float floatx4 __attribute__((ext_vector_type(4)));

__device__ __forceinline__ void gload16(const void* g, void* l) {
  // async global->LDS, 16B/lane, LDS dest = wave-uniform base + lane*16
  __builtin_amdgcn_global_load_lds(
      (__attribute__((address_space(1))) void*)const_cast<void*>(g),
      (__attribute__((address_space(3))) void*)l,
      16, 0, 0);
}

struct GArg {
  const _Float16* AH0; const _Float16* AL0;   // A region 0 (k < kcut)
  const _Float16* AH1; const _Float16* AL1;   // A region 1 (k >= kcut)
  const _Float16* BH;  const _Float16* BL;    // B transposed: [N][K], pre-offset
  const float* bias;                          // pre-offset
  _Float16* CH; _Float16* CL;                 // hi/lo fp16 out (if Cf == null), pre-offset
  float* Cf;                                  // fp32 out (if non-null)
  int fp16;                                   // 1 = hi-only operands, 1 MFMA, no CL store
};

// C = relu(A @ B^T + bias); A: M x Ktot (hi/lo fp16), B stored N x Ktot (hi/lo).
// Tile 128x128, BK=32, 256 threads (4 waves, each 64x64 = 4x4 MFMA tiles).
__global__ __launch_bounds__(256)
void gemm_split_kernel(GArg ga, GArg gb, int ldA0, int ldA1, int kcut, int Ktot, int ldC)
{
  __shared__ _Float16 sAh[128 * 32];
  __shared__ _Float16 sAl[128 * 32];
  __shared__ _Float16 sBh[128 * 32];
  __shared__ _Float16 sBl[128 * 32];

  const GArg g = (blockIdx.z == 0) ? ga : gb;
  const int fp16 = g.fp16;

  const int tid  = threadIdx.x;
  const int lane = tid & 63;
  const int wave = tid >> 6;
  const int wm = (wave >> 1) * 64;   // wave row offset in tile
  const int wn = (wave & 1) * 64;    // wave col offset in tile

  const int mBase = blockIdx.x * 128;
  const int nBase = blockIdx.y * 128;

  // staging lane coords: 16 rows/chunk, 4 lanes/row (16B each)
  const int lr  = lane >> 2;
  const int lc8 = (lane & 3) * 8;

  // fragment lane coords
  const int fr = lane & 15;
  const int fq = lane >> 4;

  floatx4 acc[4][4];
#pragma unroll
  for (int i = 0; i < 4; ++i)
#pragma unroll
    for (int j = 0; j < 4; ++j)
      acc[i][j] = (floatx4)0.0f;

  for (int kt = 0; kt < Ktot; kt += 32) {
    const _Float16* aH; const _Float16* aL; int pA; int kl;
    if (kt < kcut) { aH = g.AH0; aL = g.AL0; pA = ldA0; kl = kt; }
    else           { aH = g.AH1; aL = g.AL1; pA = ldA1; kl = kt - kcut; }

#pragma unroll
    for (int cc = 0; cc < 2; ++cc) {
      const int c = wave * 2 + cc;            // chunk 0..7 (16 rows each)
      const int arow = mBase + c * 16 + lr;
      const int brow = nBase + c * 16 + lr;
      gload16(aH   + (size_t)arow * pA   + kl + lc8, &sAh[c * 512]);
      gload16(g.BH + (size_t)brow * Ktot + kt + lc8, &sBh[c * 512]);
      if (!fp16) {
        gload16(aL   + (size_t)arow * pA   + kl + lc8, &sAl[c * 512]);
        gload16(g.BL + (size_t)brow * Ktot + kt + lc8, &sBl[c * 512]);
      }
    }
    __syncthreads();

    half8 ah[4], bh[4];
#pragma unroll
    for (int i = 0; i < 4; ++i)
      ah[i] = *(const half8*)&sAh[(wm + i * 16 + fr) * 32 + fq * 8];
#pragma unroll
    for (int j = 0; j < 4; ++j)
      bh[j] = *(const half8*)&sBh[(wn + j * 16 + fr) * 32 + fq * 8];

    if (fp16) {
#pragma unroll
      for (int i = 0; i < 4; ++i)
#pragma unroll
        for (int j = 0; j < 4; ++j)
          acc[i][j] = __builtin_amdgcn_mfma_f32_16x16x32_f16(ah[i], bh[j], acc[i][j], 0, 0, 0);
    } else {
      half8 al[4], bl[4];
#pragma unroll
      for (int i = 0; i < 4; ++i)
        al[i] = *(const half8*)&sAl[(wm + i * 16 + fr) * 32 + fq * 8];
#pragma unroll
      for (int j = 0; j < 4; ++j)
        bl[j] = *(const half8*)&sBl[(wn + j * 16 + fr) * 32 + fq * 8];
#pragma unroll
      for (int i = 0; i < 4; ++i)
#pragma unroll
        for (int j = 0; j < 4; ++j) {
          acc[i][j] = __builtin_amdgcn_mfma_f32_16x16x32_f16(al[i], bh[j], acc[i][j], 0, 0, 0);
          acc[i][j] = __builtin_amdgcn_mfma_f32_16x16x32_f16(ah[i], bl[j], acc[i][j], 0, 0, 0);
          acc[i][j] = __builtin_amdgcn_mfma_f32_16x16x32_f16(ah[i], bh[j], acc[i][j], 0, 0, 0);
        }
    }
    __syncthreads();
  }

  // epilogue: bias + relu, store fp32 or hi(/lo) fp16
#pragma unroll
  for (int j = 0; j < 4; ++j) {
    const int col = nBase + wn + j * 16 + fr;
    const float bv = g.bias[col];
#pragma unroll
    for (int i = 0; i < 4; ++i) {
#pragma unroll
      for (int r = 0; r < 4; ++r) {
        const int row = mBase + wm + i * 16 + fq * 4 + r;
        float v = acc[i][j][r] + bv;
        v = fmaxf(v, 0.0f);
        const size_t idx = (size_t)row * ldC + col;
        if (g.Cf) {
          g.Cf[idx] = v;
        } else {
          const _Float16 h = (_Float16)v;
          g.CH[idx] = h;
          if (!fp16) g.CL[idx] = (_Float16)(v - (float)h);
        }
      }
    }
  }
}

// W (K x N fp32, row-major) -> out (N x K fp16 hi/lo), i.e. transposed
__global__ void wconv_kernel(const float* __restrict__ W, int K, int N,
                             _Float16* __restrict__ oH, _Float16* __restrict__ oL) {
  int idx = blockIdx.x * 256 + threadIdx.x;   // idx = n*K + k (output-coalesced)
  if (idx >= K * N) return;
  int n = idx / K, k = idx - n * K;
  float v = W[(size_t)k * N + n];
  _Float16 h = (_Float16)v;
  oH[idx] = h;
  oL[idx] = (_Float16)(v - (float)h);
}

__global__ void bcat_kernel(const float* __restrict__ b0, const float* __restrict__ b1,
                            float* __restrict__ o) {
  int i = blockIdx.x * 256 + threadIdx.x;     // 2048 total
  o[i] = (i < 1024) ? b0[i] : b1[i - 1024];
}

__global__ void init_summary_kernel(const float* __restrict__ agg,
                                    _Float16* __restrict__ sH, _Float16* __restrict__ sL) {
  int idx = blockIdx.x * 256 + threadIdx.x;   // 8192*1024
  float v = agg[idx & 1023];
  _Float16 h = (_Float16)v;
  sH[idx] = h;
  sL[idx] = (_Float16)(v - (float)h);
}

__global__ void tow_slice_kernel(const float* __restrict__ towers, int k,
                                 _Float16* __restrict__ tH, _Float16* __restrict__ tL) {
  int idx = blockIdx.x * 256 + threadIdx.x;   // n*64 + f
  int n = idx >> 6, f = idx & 63;
  float v = towers[((size_t)n * 16 + k) * 64 + f];
  _Float16 h = (_Float16)v;
  tH[idx] = h;
  tL[idx] = (_Float16)(v - (float)h);
}

// pred = sigmoid(h2 @ OW3 + Ob3); out = (step==0) ? pred : out*pred
__global__ void gemv_pred_kernel(const float* __restrict__ h2, const float* __restrict__ w3,
                                 const float* __restrict__ b3, float* __restrict__ out, int step) {
  int row  = blockIdx.x * 4 + (threadIdx.x >> 6);
  int lane = threadIdx.x & 63;
  const float* hr = h2 + (size_t)row * 1024;
  float s = 0.0f;
#pragma unroll
  for (int j = 0; j < 1024; j += 64) s += hr[j + lane] * w3[j + lane];
#pragma unroll
  for (int off = 32; off > 0; off >>= 1) s += __shfl_down(s, off);
  if (lane == 0) {
    float p = 1.0f / (1.0f + expf(-(s + b3[0])));
    if (step == 0) out[row] = p;
    else           out[row] *= p;
  }
}

extern "C" void kernel_launch(void* const* d_in, const int* in_sizes, int n_in,
                              void* d_out, int out_size, void* d_ws, size_t ws_size,
                              hipStream_t stream) {
  const float* towers = (const float*)d_in[0];
  const float* agg    = (const float*)d_in[1];
  const float* MW1 = (const float*)d_in[2];
  const float* Mb1 = (const float*)d_in[3];
  const float* MW2 = (const float*)d_in[4];
  const float* Mb2 = (const float*)d_in[5];
  const float* MW3 = (const float*)d_in[6];
  const float* Mb3 = (const float*)d_in[7];
  const float* OW1 = (const float*)d_in[8];
  const float* Ob1 = (const float*)d_in[9];
  const float* OW2 = (const float*)d_in[10];
  const float* Ob2 = (const float*)d_in[11];
  const float* OW3 = (const float*)d_in[12];
  const float* Ob3 = (const float*)d_in[13];
  float* out = (float*)d_out;

  // ws layout (~183 MiB total)
  _Float16* p = (_Float16*)d_ws;
  _Float16* Wt1H = p; p += (size_t)2048 * 1088;
  _Float16* Wt1L = p; p += (size_t)2048 * 1088;
  _Float16* Wt2H = p; p += (size_t)2048 * 1024;   // [OW2^T ; MW2^T]
  _Float16* Wt2L = p; p += (size_t)2048 * 1024;
  _Float16* Wt3H = p; p += (size_t)1024 * 1024;
  _Float16* Wt3L = p; p += (size_t)1024 * 1024;
  _Float16* sumH = p; p += (size_t)8192 * 1024;
  _Float16* sumL = p; p += (size_t)8192 * 1024;
  _Float16* Y1H  = p; p += (size_t)8192 * 2048;   // [h1 | m1] hi
  _Float16* Y1L  = p; p += (size_t)8192 * 2048;   // lo (m-half only used)
  _Float16* m2H  = p; p += (size_t)8192 * 1024;
  _Float16* m2L  = p; p += (size_t)8192 * 1024;
  _Float16* towH = p; p += (size_t)8192 * 64;
  _Float16* towL = p; p += (size_t)8192 * 64;
  float* h2f  = (float*)p; p += (size_t)8192 * 1024 * 2;
  float* b1ws = (float*)p; p += 4096;

  // per-call setup: convert weights (transposed, hi/lo), concat bias1, init summary
  {
    int tot = 1088 * 1024;
    wconv_kernel<<<dim3((tot + 255) / 256), dim3(256), 0, stream>>>(OW1, 1088, 1024, Wt1H, Wt1L);
    wconv_kernel<<<dim3((tot + 255) / 256), dim3(256), 0, stream>>>(MW1, 1088, 1024,
        Wt1H + (size_t)1024 * 1088, Wt1L + (size_t)1024 * 1088);
    tot = 1024 * 1024;
    wconv_kernel<<<dim3((tot + 255) / 256), dim3(256), 0, stream>>>(OW2, 1024, 1024, Wt2H, Wt2L);
    wconv_kernel<<<dim3((tot + 255) / 256), dim3(256), 0, stream>>>(MW2, 1024, 1024,
        Wt2H + (size_t)1024 * 1024, Wt2L + (size_t)1024 * 1024);
    wconv_kernel<<<dim3((tot + 255) / 256), dim3(256), 0, stream>>>(MW3, 1024, 1024, Wt3H, Wt3L);
    bcat_kernel<<<dim3(8), dim3(256), 0, stream>>>(Ob1, Mb1, b1ws);
    init_summary_kernel<<<dim3(32768), dim3(256), 0, stream>>>(agg, sumH, sumL);
  }

  for (int k = 0; k < 16; ++k) {
    tow_slice_kernel<<<dim3(2048), dim3(256), 0, stream>>>(towers, k, towH, towL);

    // K1: x=[summary | tower_k] (K=1088) @ Wt1 -> Y1=[h1|m1] (N=2048)
    // z=0: h-half (fp16 fast path), z=1: m-half (3-MFMA split)
    GArg a1; a1.AH0 = sumH; a1.AL0 = sumL; a1.AH1 = towH; a1.AL1 = towL;
    a1.BH = Wt1H; a1.BL = Wt1L; a1.bias = b1ws;
    a1.CH = Y1H; a1.CL = Y1L; a1.Cf = nullptr; a1.fp16 = 1;
    GArg b1 = a1;
    b1.BH = Wt1H + (size_t)1024 * 1088; b1.BL = Wt1L + (size_t)1024 * 1088;
    b1.bias = b1ws + 1024; b1.CH = Y1H + 1024; b1.CL = Y1L + 1024; b1.fp16 = 0;
    gemm_split_kernel<<<dim3(64, 8, 2), dim3(256), 0, stream>>>(a1, b1, 1024, 64, 1024, 1088, 2048);

    // K2 batched: z=0 h1@OW2 -> h2 (fp32 out, fp16 fast path); z=1 m1@MW2 -> m2 (split)
    GArg a2; a2.AH0 = Y1H; a2.AL0 = Y1L; a2.AH1 = Y1H; a2.AL1 = Y1L;
    a2.BH = Wt2H; a2.BL = Wt2L; a2.bias = Ob2;
    a2.CH = nullptr; a2.CL = nullptr; a2.Cf = h2f; a2.fp16 = 1;
    GArg b2; b2.AH0 = Y1H + 1024; b2.AL0 = Y1L + 1024; b2.AH1 = Y1H + 1024; b2.AL1 = Y1L + 1024;
    b2.BH = Wt2H + (size_t)1024 * 1024; b2.BL = Wt2L + (size_t)1024 * 1024; b2.bias = Mb2;
    b2.CH = m2H; b2.CL = m2L; b2.Cf = nullptr; b2.fp16 = 0;
    gemm_split_kernel<<<dim3(64, 8, 2), dim3(256), 0, stream>>>(a2, b2, 2048, 2048, 1024, 1024, 1024);

    // K3: m2 @ MW3 -> summary (split; in-place safe: K1 already consumed summary)
    GArg a3; a3.AH0 = m2H; a3.AL0 = m2L; a3.AH1 = m2H; a3.AL1 = m2L;
    a3.BH = Wt3H; a3.BL = Wt3L; a3.bias = Mb3;
    a3.CH = sumH; a3.CL = sumL; a3.Cf = nullptr; a3.fp16 = 0;
    gemm_split_kernel<<<dim3(64, 8, 1), dim3(256), 0, stream>>>(a3, a3, 1024, 1024, 1024, 1024, 1024);

    // K4: pred + product accumulate
    gemv_pred_kernel<<<dim3(2048), dim3(256), 0, stream>>>(h2f, OW3, Ob3, out, k);
  }
}

// Round 3
// 4222.463 us; speedup vs baseline: 1.1075x; 1.0525x over previous
//
#include <hip/hip_runtime.h>
#include <cstdint>
#include <cstddef>

// BottomUpNet: N=8192 rows independent; K=16 sequential steps.
// m-chain (summary recurrence): fp16 hi/lo split, 3 MFMAs => ~fp32 exact.
// h-chain (h1,h2 -> pred): plain fp16, 1 MFMA (per-pred err ~5e-4, non-compounding).
// R3: LPT block ordering (split z=0 first), pred-GEMV fused into K2 epilogue
// (atomicAdd partial dots), tower slicing hoisted to setup.

typedef _Float16 half8 __attribute__((ext_vector_type(8)));
typedef float floatx4 __attribute__((ext_vector_type(4)));

__device__ __forceinline__ void gload16(const void* g, void* l) {
  // async global->LDS, 16B/lane, LDS dest = wave-uniform base + lane*16
  __builtin_amdgcn_global_load_lds(
      (__attribute__((address_space(1))) void*)const_cast<void*>(g),
      (__attribute__((address_space(3))) void*)l,
      16, 0, 0);
}

struct GArg {
  const _Float16* AH0; const _Float16* AL0;   // A region 0 (k < kcut)
  const _Float16* AH1; const _Float16* AL1;   // A region 1 (k >= kcut)
  const _Float16* BH;  const _Float16* BL;    // B transposed: [N][K], pre-offset
  const float* bias;                          // pre-offset
  _Float16* CH; _Float16* CL;                 // hi/lo fp16 out, pre-offset
  const float* w3;                            // if sacc: per-col weight for partial dot
  float* sacc;                                // if non-null: atomicAdd partial dots, no C store
  int fp16;                                   // 1 = hi-only operands, 1 MFMA, no CL store
};

// C = relu(A @ B^T + bias); A: M x Ktot (hi/lo fp16), B stored N x Ktot (hi/lo).
// Tile 128x128, BK=32, 256 threads (4 waves, each 64x64 = 4x4 MFMA tiles).
__global__ __launch_bounds__(256)
void gemm_split_kernel(GArg ga, GArg gb, int ldA0, int ldA1, int kcut, int Ktot, int ldC)
{
  __shared__ _Float16 sAh[128 * 32];
  __shared__ _Float16 sAl[128 * 32];
  __shared__ _Float16 sBh[128 * 32];
  __shared__ _Float16 sBl[128 * 32];

  const GArg g = (blockIdx.z == 0) ? ga : gb;
  const int fp16 = g.fp16;

  const int tid  = threadIdx.x;
  const int lane = tid & 63;
  const int wave = tid >> 6;
  const int wm = (wave >> 1) * 64;   // wave row offset in tile
  const int wn = (wave & 1) * 64;    // wave col offset in tile

  const int mBase = blockIdx.x * 128;
  const int nBase = blockIdx.y * 128;

  // staging lane coords: 16 rows/chunk, 4 lanes/row (16B each)
  const int lr  = lane >> 2;
  const int lc8 = (lane & 3) * 8;

  // fragment lane coords
  const int fr = lane & 15;
  const int fq = lane >> 4;

  floatx4 acc[4][4];
#pragma unroll
  for (int i = 0; i < 4; ++i)
#pragma unroll
    for (int j = 0; j < 4; ++j)
      acc[i][j] = (floatx4)0.0f;

  for (int kt = 0; kt < Ktot; kt += 32) {
    const _Float16* aH; const _Float16* aL; int pA; int kl;
    if (kt < kcut) { aH = g.AH0; aL = g.AL0; pA = ldA0; kl = kt; }
    else           { aH = g.AH1; aL = g.AL1; pA = ldA1; kl = kt - kcut; }

#pragma unroll
    for (int cc = 0; cc < 2; ++cc) {
      const int c = wave * 2 + cc;            // chunk 0..7 (16 rows each)
      const int arow = mBase + c * 16 + lr;
      const int brow = nBase + c * 16 + lr;
      gload16(aH   + (size_t)arow * pA   + kl + lc8, &sAh[c * 512]);
      gload16(g.BH + (size_t)brow * Ktot + kt + lc8, &sBh[c * 512]);
      if (!fp16) {
        gload16(aL   + (size_t)arow * pA   + kl + lc8, &sAl[c * 512]);
        gload16(g.BL + (size_t)brow * Ktot + kt + lc8, &sBl[c * 512]);
      }
    }
    __syncthreads();

    half8 ah[4], bh[4];
#pragma unroll
    for (int i = 0; i < 4; ++i)
      ah[i] = *(const half8*)&sAh[(wm + i * 16 + fr) * 32 + fq * 8];
#pragma unroll
    for (int j = 0; j < 4; ++j)
      bh[j] = *(const half8*)&sBh[(wn + j * 16 + fr) * 32 + fq * 8];

    if (fp16) {
#pragma unroll
      for (int i = 0; i < 4; ++i)
#pragma unroll
        for (int j = 0; j < 4; ++j)
          acc[i][j] = __builtin_amdgcn_mfma_f32_16x16x32_f16(ah[i], bh[j], acc[i][j], 0, 0, 0);
    } else {
      half8 al[4], bl[4];
#pragma unroll
      for (int i = 0; i < 4; ++i)
        al[i] = *(const half8*)&sAl[(wm + i * 16 + fr) * 32 + fq * 8];
#pragma unroll
      for (int j = 0; j < 4; ++j)
        bl[j] = *(const half8*)&sBl[(wn + j * 16 + fr) * 32 + fq * 8];
#pragma unroll
      for (int i = 0; i < 4; ++i)
#pragma unroll
        for (int j = 0; j < 4; ++j) {
          acc[i][j] = __builtin_amdgcn_mfma_f32_16x16x32_f16(al[i], bh[j], acc[i][j], 0, 0, 0);
          acc[i][j] = __builtin_amdgcn_mfma_f32_16x16x32_f16(ah[i], bl[j], acc[i][j], 0, 0, 0);
          acc[i][j] = __builtin_amdgcn_mfma_f32_16x16x32_f16(ah[i], bh[j], acc[i][j], 0, 0, 0);
        }
    }
    __syncthreads();
  }

  // epilogue
  float bv[4], w3v[4];
#pragma unroll
  for (int j = 0; j < 4; ++j) {
    const int col = nBase + wn + j * 16 + fr;
    bv[j] = g.bias[col];
    w3v[j] = g.sacc ? g.w3[col] : 0.0f;
  }

  if (g.sacc) {
    // fused pred partial: p[row] += sum_j relu(acc+bias)*w3; no C store
#pragma unroll
    for (int i = 0; i < 4; ++i) {
#pragma unroll
      for (int r = 0; r < 4; ++r) {
        float pr = 0.0f;
#pragma unroll
        for (int j = 0; j < 4; ++j) {
          float v = fmaxf(acc[i][j][r] + bv[j], 0.0f);
          pr += v * w3v[j];
        }
        pr += __shfl_xor(pr, 1);
        pr += __shfl_xor(pr, 2);
        pr += __shfl_xor(pr, 4);
        pr += __shfl_xor(pr, 8);
        if (fr == 0)
          atomicAdd(&g.sacc[mBase + wm + i * 16 + fq * 4 + r], pr);
      }
    }
  } else {
#pragma unroll
    for (int j = 0; j < 4; ++j) {
#pragma unroll
      for (int i = 0; i < 4; ++i) {
#pragma unroll
        for (int r = 0; r < 4; ++r) {
          const int row = mBase + wm + i * 16 + fq * 4 + r;
          const int col = nBase + wn + j * 16 + fr;
          float v = fmaxf(acc[i][j][r] + bv[j], 0.0f);
          const size_t idx = (size_t)row * ldC + col;
          const _Float16 h = (_Float16)v;
          g.CH[idx] = h;
          if (!fp16) g.CL[idx] = (_Float16)(v - (float)h);
        }
      }
    }
  }
}

// W (K x N fp32, row-major) -> out (N x K fp16 hi/lo), i.e. transposed
__global__ void wconv_kernel(const float* __restrict__ W, int K, int N,
                             _Float16* __restrict__ oH, _Float16* __restrict__ oL) {
  int idx = blockIdx.x * 256 + threadIdx.x;   // idx = n*K + k (output-coalesced)
  if (idx >= K * N) return;
  int n = idx / K, k = idx - n * K;
  float v = W[(size_t)k * N + n];
  _Float16 h = (_Float16)v;
  oH[idx] = h;
  oL[idx] = (_Float16)(v - (float)h);
}

__global__ void bcat_kernel(const float* __restrict__ b0, const float* __restrict__ b1,
                            float* __restrict__ o) {
  int i = blockIdx.x * 256 + threadIdx.x;     // 2048 total
  o[i] = (i < 1024) ? b0[i] : b1[i - 1024];
}

__global__ void init_summary_kernel(const float* __restrict__ agg,
                                    _Float16* __restrict__ sH, _Float16* __restrict__ sL,
                                    float* __restrict__ sacc) {
  int idx = blockIdx.x * 256 + threadIdx.x;   // 8192*1024
  float v = agg[idx & 1023];
  _Float16 h = (_Float16)v;
  sH[idx] = h;
  sL[idx] = (_Float16)(v - (float)h);
  if (idx < 8192) sacc[idx] = 0.0f;
}

// towers [n][k][f] fp32 -> towAll [k][n][f] fp16 hi/lo (all 16 slices at once)
__global__ void tow_conv_all_kernel(const float* __restrict__ towers,
                                    _Float16* __restrict__ oH, _Float16* __restrict__ oL) {
  size_t idx = (size_t)blockIdx.x * 256 + threadIdx.x;  // (k*8192+n)*64+f
  int f = idx & 63;
  int n = (int)((idx >> 6) & 8191);
  int k = (int)(idx >> 19);
  float v = towers[((size_t)n * 16 + k) * 64 + f];
  _Float16 h = (_Float16)v;
  oH[idx] = h;
  oL[idx] = (_Float16)(v - (float)h);
}

// pred = sigmoid(sacc + Ob3); out *= pred; re-zero sacc for next step
__global__ void pred_final_kernel(float* __restrict__ sacc, const float* __restrict__ b3,
                                  float* __restrict__ out, int step) {
  int row = blockIdx.x * 256 + threadIdx.x;   // 8192
  float p = 1.0f / (1.0f + expf(-(sacc[row] + b3[0])));
  out[row] = (step == 0) ? p : out[row] * p;
  sacc[row] = 0.0f;
}

extern "C" void kernel_launch(void* const* d_in, const int* in_sizes, int n_in,
                              void* d_out, int out_size, void* d_ws, size_t ws_size,
                              hipStream_t stream) {
  const float* towers = (const float*)d_in[0];
  const float* agg    = (const float*)d_in[1];
  const float* MW1 = (const float*)d_in[2];
  const float* Mb1 = (const float*)d_in[3];
  const float* MW2 = (const float*)d_in[4];
  const float* Mb2 = (const float*)d_in[5];
  const float* MW3 = (const float*)d_in[6];
  const float* Mb3 = (const float*)d_in[7];
  const float* OW1 = (const float*)d_in[8];
  const float* Ob1 = (const float*)d_in[9];
  const float* OW2 = (const float*)d_in[10];
  const float* Ob2 = (const float*)d_in[11];
  const float* OW3 = (const float*)d_in[12];
  const float* Ob3 = (const float*)d_in[13];
  float* out = (float*)d_out;

  // ws layout (~188 MiB total)
  _Float16* p = (_Float16*)d_ws;
  _Float16* Wt1H = p; p += (size_t)2048 * 1088;
  _Float16* Wt1L = p; p += (size_t)2048 * 1088;
  _Float16* Wt2H = p; p += (size_t)2048 * 1024;   // [OW2^T ; MW2^T]
  _Float16* Wt2L = p; p += (size_t)2048 * 1024;
  _Float16* Wt3H = p; p += (size_t)1024 * 1024;
  _Float16* Wt3L = p; p += (size_t)1024 * 1024;
  _Float16* sumH = p; p += (size_t)8192 * 1024;
  _Float16* sumL = p; p += (size_t)8192 * 1024;
  _Float16* Y1H  = p; p += (size_t)8192 * 2048;   // [h1 | m1] hi
  _Float16* Y1L  = p; p += (size_t)8192 * 2048;   // lo (m-half only used)
  _Float16* m2H  = p; p += (size_t)8192 * 1024;
  _Float16* m2L  = p; p += (size_t)8192 * 1024;
  _Float16* towAllH = p; p += (size_t)16 * 8192 * 64;
  _Float16* towAllL = p; p += (size_t)16 * 8192 * 64;
  float* sacc = (float*)p; p += 8192 * 2;
  float* b1ws = (float*)p; p += 4096;

  // per-call setup
  {
    int tot = 1088 * 1024;
    wconv_kernel<<<dim3((tot + 255) / 256), dim3(256), 0, stream>>>(OW1, 1088, 1024, Wt1H, Wt1L);
    wconv_kernel<<<dim3((tot + 255) / 256), dim3(256), 0, stream>>>(MW1, 1088, 1024,
        Wt1H + (size_t)1024 * 1088, Wt1L + (size_t)1024 * 1088);
    tot = 1024 * 1024;
    wconv_kernel<<<dim3((tot + 255) / 256), dim3(256), 0, stream>>>(OW2, 1024, 1024, Wt2H, Wt2L);
    wconv_kernel<<<dim3((tot + 255) / 256), dim3(256), 0, stream>>>(MW2, 1024, 1024,
        Wt2H + (size_t)1024 * 1024, Wt2L + (size_t)1024 * 1024);
    wconv_kernel<<<dim3((tot + 255) / 256), dim3(256), 0, stream>>>(MW3, 1024, 1024, Wt3H, Wt3L);
    bcat_kernel<<<dim3(8), dim3(256), 0, stream>>>(Ob1, Mb1, b1ws);
    init_summary_kernel<<<dim3(32768), dim3(256), 0, stream>>>(agg, sumH, sumL, sacc);
    tow_conv_all_kernel<<<dim3(32768), dim3(256), 0, stream>>>(towers, towAllH, towAllL);
  }

  for (int k = 0; k < 16; ++k) {
    const _Float16* towH = towAllH + (size_t)k * 8192 * 64;
    const _Float16* towL = towAllL + (size_t)k * 8192 * 64;

    // K1: x=[summary | tower_k] (K=1088) @ Wt1 -> Y1=[h1|m1] (N=2048)
    // LPT: z=0 = m-half (slow split), z=1 = h-half (fast fp16)
    GArg m1g; m1g.AH0 = sumH; m1g.AL0 = sumL; m1g.AH1 = towH; m1g.AL1 = towL;
    m1g.BH = Wt1H + (size_t)1024 * 1088; m1g.BL = Wt1L + (size_t)1024 * 1088;
    m1g.bias = b1ws + 1024; m1g.CH = Y1H + 1024; m1g.CL = Y1L + 1024;
    m1g.w3 = nullptr; m1g.sacc = nullptr; m1g.fp16 = 0;
    GArg h1g = m1g;
    h1g.BH = Wt1H; h1g.BL = Wt1L; h1g.bias = b1ws; h1g.CH = Y1H; h1g.CL = Y1L; h1g.fp16 = 1;
    gemm_split_kernel<<<dim3(64, 8, 2), dim3(256), 0, stream>>>(m1g, h1g, 1024, 64, 1024, 1088, 2048);

    // K2: z=0 m1@MW2 -> m2 (split); z=1 h1@OW2 -> fused relu+dot(OW3) atomics (fp16)
    GArg m2g; m2g.AH0 = Y1H + 1024; m2g.AL0 = Y1L + 1024; m2g.AH1 = Y1H + 1024; m2g.AL1 = Y1L + 1024;
    m2g.BH = Wt2H + (size_t)1024 * 1024; m2g.BL = Wt2L + (size_t)1024 * 1024; m2g.bias = Mb2;
    m2g.CH = m2H; m2g.CL = m2L; m2g.w3 = nullptr; m2g.sacc = nullptr; m2g.fp16 = 0;
    GArg h2g; h2g.AH0 = Y1H; h2g.AL0 = Y1L; h2g.AH1 = Y1H; h2g.AL1 = Y1L;
    h2g.BH = Wt2H; h2g.BL = Wt2L; h2g.bias = Ob2;
    h2g.CH = nullptr; h2g.CL = nullptr; h2g.w3 = OW3; h2g.sacc = sacc; h2g.fp16 = 1;
    gemm_split_kernel<<<dim3(64, 8, 2), dim3(256), 0, stream>>>(m2g, h2g, 2048, 2048, 1024, 1024, 1024);

    // K3: m2 @ MW3 -> summary (split; in-place safe: K1 already consumed summary)
    GArg m3g; m3g.AH0 = m2H; m3g.AL0 = m2L; m3g.AH1 = m2H; m3g.AL1 = m2L;
    m3g.BH = Wt3H; m3g.BL = Wt3L; m3g.bias = Mb3;
    m3g.CH = sumH; m3g.CL = sumL; m3g.w3 = nullptr; m3g.sacc = nullptr; m3g.fp16 = 0;
    gemm_split_kernel<<<dim3(64, 8, 1), dim3(256), 0, stream>>>(m3g, m3g, 1024, 1024, 1024, 1024, 1024);

    // K4: finalize pred, accumulate product, re-zero sacc
    pred_final_kernel<<<dim3(32), dim3(256), 0, stream>>>(sacc, Ob3, out, k);
  }
}

// Round 4
// 4118.885 us; speedup vs baseline: 1.1354x; 1.0251x over previous
//
#include <hip/hip_runtime.h>
#include <cstdint>
#include <cstddef>

// BottomUpNet: N=8192 rows independent; K=16 sequential steps.
// m-chain (summary recurrence): fp16 hi/lo split, 3 MFMAs => ~fp32 exact.
// h-chain (h1,h2 -> pred): plain fp16, 1 MFMA (non-compounding).
// R4: pure-speed 512-block dispatches (no mixed split/fp16 populations),
// 32x32x16 MFMA shape (half the issue slots, +15% pipe ceiling),
// __launch_bounds__(256,3) + per-khalf frag loads for 3 waves/SIMD occupancy.

typedef _Float16 f16x8 __attribute__((ext_vector_type(8)));
typedef float f32x16 __attribute__((ext_vector_type(16)));

__device__ __forceinline__ void gload16(const void* g, void* l) {
  // async global->LDS, 16B/lane, LDS dest = wave-uniform base + lane*16
  __builtin_amdgcn_global_load_lds(
      (__attribute__((address_space(1))) void*)const_cast<void*>(g),
      (__attribute__((address_space(3))) void*)l,
      16, 0, 0);
}

// ---- split GEMM: C = relu(A@B^T + bias), A,B,C hi/lo fp16 (3 MFMAs => ~fp32)
// Tile 128x128, BK=32, 256 thr (4 waves, each 64x64 = 2x2 of 32x32 MFMA tiles).
__global__ __launch_bounds__(256, 3)
void gemm_split_kernel(const _Float16* __restrict__ AH0, const _Float16* __restrict__ AL0, int ldA0,
                       const _Float16* __restrict__ AH1, const _Float16* __restrict__ AL1, int ldA1,
                       int kcut, int Ktot,
                       const _Float16* __restrict__ BH, const _Float16* __restrict__ BL,
                       const float* __restrict__ bias,
                       _Float16* __restrict__ CH, _Float16* __restrict__ CL, int ldC)
{
  __shared__ _Float16 sAh[128 * 32];
  __shared__ _Float16 sAl[128 * 32];
  __shared__ _Float16 sBh[128 * 32];
  __shared__ _Float16 sBl[128 * 32];

  const int lane = threadIdx.x & 63;
  const int wave = threadIdx.x >> 6;
  const int wm = (wave >> 1) * 64, wn = (wave & 1) * 64;
  const int mBase = blockIdx.x * 128, nBase = blockIdx.y * 128;
  const int lr = lane >> 2, lc8 = (lane & 3) * 8;   // staging coords
  const int l31 = lane & 31, l5 = lane >> 5;        // fragment coords

  f32x16 acc[2][2];
#pragma unroll
  for (int i = 0; i < 2; ++i)
#pragma unroll
    for (int j = 0; j < 2; ++j)
      acc[i][j] = (f32x16)0.0f;

  for (int kt = 0; kt < Ktot; kt += 32) {
    const _Float16 *aH, *aL; int pA, kl;
    if (kt < kcut) { aH = AH0; aL = AL0; pA = ldA0; kl = kt; }
    else           { aH = AH1; aL = AL1; pA = ldA1; kl = kt - kcut; }

#pragma unroll
    for (int cc = 0; cc < 2; ++cc) {
      const int c = wave * 2 + cc;                  // chunk 0..7, 16 rows each
      const int arow = mBase + c * 16 + lr;
      const int brow = nBase + c * 16 + lr;
      gload16(aH + (size_t)arow * pA   + kl + lc8, &sAh[c * 512]);
      gload16(aL + (size_t)arow * pA   + kl + lc8, &sAl[c * 512]);
      gload16(BH + (size_t)brow * Ktot + kt + lc8, &sBh[c * 512]);
      gload16(BL + (size_t)brow * Ktot + kt + lc8, &sBl[c * 512]);
    }
    __syncthreads();

#pragma unroll
    for (int kh = 0; kh < 2; ++kh) {                // two K=16 MFMAs per BK=32
      const int ko = kh * 16 + l5 * 8;
      f16x8 ah[2], al[2], bh[2], bl[2];
#pragma unroll
      for (int i = 0; i < 2; ++i) {
        const int off = (wm + i * 32 + l31) * 32 + ko;
        ah[i] = *(const f16x8*)&sAh[off];
        al[i] = *(const f16x8*)&sAl[off];
      }
#pragma unroll
      for (int j = 0; j < 2; ++j) {
        const int off = (wn + j * 32 + l31) * 32 + ko;
        bh[j] = *(const f16x8*)&sBh[off];
        bl[j] = *(const f16x8*)&sBl[off];
      }
#pragma unroll
      for (int i = 0; i < 2; ++i)
#pragma unroll
        for (int j = 0; j < 2; ++j) {
          acc[i][j] = __builtin_amdgcn_mfma_f32_32x32x16_f16(al[i], bh[j], acc[i][j], 0, 0, 0);
          acc[i][j] = __builtin_amdgcn_mfma_f32_32x32x16_f16(ah[i], bl[j], acc[i][j], 0, 0, 0);
          acc[i][j] = __builtin_amdgcn_mfma_f32_32x32x16_f16(ah[i], bh[j], acc[i][j], 0, 0, 0);
        }
    }
    __syncthreads();
  }

  float bv[2];
#pragma unroll
  for (int j = 0; j < 2; ++j) bv[j] = bias[nBase + wn + j * 32 + l31];
#pragma unroll
  for (int i = 0; i < 2; ++i)
#pragma unroll
    for (int j = 0; j < 2; ++j)
#pragma unroll
      for (int r = 0; r < 16; ++r) {
        const int row = mBase + wm + i * 32 + (r & 3) + 8 * (r >> 2) + 4 * l5;
        const int col = nBase + wn + j * 32 + l31;
        float v = fmaxf(acc[i][j][r] + bv[j], 0.0f);
        const size_t idx = (size_t)row * ldC + col;
        const _Float16 h = (_Float16)v;
        CH[idx] = h;
        CL[idx] = (_Float16)(v - (float)h);
      }
}

// ---- fp16 GEMM (hi-only, 1 MFMA): C = relu(A@B^T + bias) fp16 out,
// or fused-pred mode (sacc != null): sacc[row] += sum_col relu(.)*w3[col]
__global__ __launch_bounds__(256, 3)
void gemm_h_kernel(const _Float16* __restrict__ A0, int ldA0,
                   const _Float16* __restrict__ A1, int ldA1,
                   int kcut, int Ktot,
                   const _Float16* __restrict__ B,
                   const float* __restrict__ bias,
                   _Float16* __restrict__ C, int ldC,
                   const float* __restrict__ w3, float* __restrict__ sacc)
{
  __shared__ _Float16 sAh[128 * 32];
  __shared__ _Float16 sBh[128 * 32];

  const int lane = threadIdx.x & 63;
  const int wave = threadIdx.x >> 6;
  const int wm = (wave >> 1) * 64, wn = (wave & 1) * 64;
  const int mBase = blockIdx.x * 128, nBase = blockIdx.y * 128;
  const int lr = lane >> 2, lc8 = (lane & 3) * 8;
  const int l31 = lane & 31, l5 = lane >> 5;

  f32x16 acc[2][2];
#pragma unroll
  for (int i = 0; i < 2; ++i)
#pragma unroll
    for (int j = 0; j < 2; ++j)
      acc[i][j] = (f32x16)0.0f;

  for (int kt = 0; kt < Ktot; kt += 32) {
    const _Float16* aH; int pA, kl;
    if (kt < kcut) { aH = A0; pA = ldA0; kl = kt; }
    else           { aH = A1; pA = ldA1; kl = kt - kcut; }

#pragma unroll
    for (int cc = 0; cc < 2; ++cc) {
      const int c = wave * 2 + cc;
      const int arow = mBase + c * 16 + lr;
      const int brow = nBase + c * 16 + lr;
      gload16(aH + (size_t)arow * pA  + kl + lc8, &sAh[c * 512]);
      gload16(B  + (size_t)brow * Ktot + kt + lc8, &sBh[c * 512]);
    }
    __syncthreads();

#pragma unroll
    for (int kh = 0; kh < 2; ++kh) {
      const int ko = kh * 16 + l5 * 8;
      f16x8 ah[2], bh[2];
#pragma unroll
      for (int i = 0; i < 2; ++i)
        ah[i] = *(const f16x8*)&sAh[(wm + i * 32 + l31) * 32 + ko];
#pragma unroll
      for (int j = 0; j < 2; ++j)
        bh[j] = *(const f16x8*)&sBh[(wn + j * 32 + l31) * 32 + ko];
#pragma unroll
      for (int i = 0; i < 2; ++i)
#pragma unroll
        for (int j = 0; j < 2; ++j)
          acc[i][j] = __builtin_amdgcn_mfma_f32_32x32x16_f16(ah[i], bh[j], acc[i][j], 0, 0, 0);
    }
    __syncthreads();
  }

  float bv[2], w3v[2];
#pragma unroll
  for (int j = 0; j < 2; ++j) {
    const int col = nBase + wn + j * 32 + l31;
    bv[j] = bias[col];
    w3v[j] = sacc ? w3[col] : 0.0f;
  }

  if (sacc) {
    // fused pred partial: one value per C/D row, reduced over the 32 col-lanes
#pragma unroll
    for (int i = 0; i < 2; ++i)
#pragma unroll
      for (int r = 0; r < 16; ++r) {
        float pr = 0.0f;
#pragma unroll
        for (int j = 0; j < 2; ++j)
          pr += fmaxf(acc[i][j][r] + bv[j], 0.0f) * w3v[j];
        pr += __shfl_xor(pr, 1);
        pr += __shfl_xor(pr, 2);
        pr += __shfl_xor(pr, 4);
        pr += __shfl_xor(pr, 8);
        pr += __shfl_xor(pr, 16);
        if (l31 == 0)
          atomicAdd(&sacc[mBase + wm + i * 32 + (r & 3) + 8 * (r >> 2) + 4 * l5], pr);
      }
  } else {
#pragma unroll
    for (int i = 0; i < 2; ++i)
#pragma unroll
      for (int j = 0; j < 2; ++j)
#pragma unroll
        for (int r = 0; r < 16; ++r) {
          const int row = mBase + wm + i * 32 + (r & 3) + 8 * (r >> 2) + 4 * l5;
          const int col = nBase + wn + j * 32 + l31;
          float v = fmaxf(acc[i][j][r] + bv[j], 0.0f);
          C[(size_t)row * ldC + col] = (_Float16)v;
        }
  }
}

// W (K x N fp32, row-major) -> out (N x K fp16 hi[/lo]), i.e. transposed
__global__ void wconv_kernel(const float* __restrict__ W, int K, int N,
                             _Float16* __restrict__ oH, _Float16* __restrict__ oL) {
  int idx = blockIdx.x * 256 + threadIdx.x;   // idx = n*K + k (output-coalesced)
  if (idx >= K * N) return;
  int n = idx / K, k = idx - n * K;
  float v = W[(size_t)k * N + n];
  _Float16 h = (_Float16)v;
  oH[idx] = h;
  if (oL) oL[idx] = (_Float16)(v - (float)h);
}

__global__ void init_summary_kernel(const float* __restrict__ agg,
                                    _Float16* __restrict__ sH, _Float16* __restrict__ sL,
                                    float* __restrict__ sacc) {
  int idx = blockIdx.x * 256 + threadIdx.x;   // 8192*1024
  float v = agg[idx & 1023];
  _Float16 h = (_Float16)v;
  sH[idx] = h;
  sL[idx] = (_Float16)(v - (float)h);
  if (idx < 8192) sacc[idx] = 0.0f;
}

// towers [n][k][f] fp32 -> towAll [k][n][f] fp16 hi/lo (all 16 slices)
__global__ void tow_conv_all_kernel(const float* __restrict__ towers,
                                    _Float16* __restrict__ oH, _Float16* __restrict__ oL) {
  size_t idx = (size_t)blockIdx.x * 256 + threadIdx.x;  // (k*8192+n)*64+f
  int f = idx & 63;
  int n = (int)((idx >> 6) & 8191);
  int k = (int)(idx >> 19);
  float v = towers[((size_t)n * 16 + k) * 64 + f];
  _Float16 h = (_Float16)v;
  oH[idx] = h;
  oL[idx] = (_Float16)(v - (float)h);
}

// pred = sigmoid(sacc + Ob3); out *= pred; re-zero sacc for next step
__global__ void pred_final_kernel(float* __restrict__ sacc, const float* __restrict__ b3,
                                  float* __restrict__ out, int step) {
  int row = blockIdx.x * 256 + threadIdx.x;   // 8192
  float p = 1.0f / (1.0f + expf(-(sacc[row] + b3[0])));
  out[row] = (step == 0) ? p : out[row] * p;
  sacc[row] = 0.0f;
}

extern "C" void kernel_launch(void* const* d_in, const int* in_sizes, int n_in,
                              void* d_out, int out_size, void* d_ws, size_t ws_size,
                              hipStream_t stream) {
  const float* towers = (const float*)d_in[0];
  const float* agg    = (const float*)d_in[1];
  const float* MW1 = (const float*)d_in[2];
  const float* Mb1 = (const float*)d_in[3];
  const float* MW2 = (const float*)d_in[4];
  const float* Mb2 = (const float*)d_in[5];
  const float* MW3 = (const float*)d_in[6];
  const float* Mb3 = (const float*)d_in[7];
  const float* OW1 = (const float*)d_in[8];
  const float* Ob1 = (const float*)d_in[9];
  const float* OW2 = (const float*)d_in[10];
  const float* Ob2 = (const float*)d_in[11];
  const float* OW3 = (const float*)d_in[12];
  const float* Ob3 = (const float*)d_in[13];
  float* out = (float*)d_out;

  // ws layout (~168 MiB)
  _Float16* p = (_Float16*)d_ws;
  _Float16* MW1tH = p; p += (size_t)1024 * 1088;
  _Float16* MW1tL = p; p += (size_t)1024 * 1088;
  _Float16* OW1tH = p; p += (size_t)1024 * 1088;
  _Float16* MW2tH = p; p += (size_t)1024 * 1024;
  _Float16* MW2tL = p; p += (size_t)1024 * 1024;
  _Float16* OW2tH = p; p += (size_t)1024 * 1024;
  _Float16* MW3tH = p; p += (size_t)1024 * 1024;
  _Float16* MW3tL = p; p += (size_t)1024 * 1024;
  _Float16* sumH  = p; p += (size_t)8192 * 1024;
  _Float16* sumL  = p; p += (size_t)8192 * 1024;
  _Float16* m1H   = p; p += (size_t)8192 * 1024;
  _Float16* m1L   = p; p += (size_t)8192 * 1024;
  _Float16* h1    = p; p += (size_t)8192 * 1024;
  _Float16* m2H   = p; p += (size_t)8192 * 1024;
  _Float16* m2L   = p; p += (size_t)8192 * 1024;
  _Float16* towAllH = p; p += (size_t)16 * 8192 * 64;
  _Float16* towAllL = p; p += (size_t)16 * 8192 * 64;
  float* sacc = (float*)p;

  // per-call setup: transpose+split weights, convert towers, init summary
  {
    int tot = 1088 * 1024;
    wconv_kernel<<<dim3((tot + 255) / 256), dim3(256), 0, stream>>>(MW1, 1088, 1024, MW1tH, MW1tL);
    wconv_kernel<<<dim3((tot + 255) / 256), dim3(256), 0, stream>>>(OW1, 1088, 1024, OW1tH, nullptr);
    tot = 1024 * 1024;
    wconv_kernel<<<dim3((tot + 255) / 256), dim3(256), 0, stream>>>(MW2, 1024, 1024, MW2tH, MW2tL);
    wconv_kernel<<<dim3((tot + 255) / 256), dim3(256), 0, stream>>>(OW2, 1024, 1024, OW2tH, nullptr);
    wconv_kernel<<<dim3((tot + 255) / 256), dim3(256), 0, stream>>>(MW3, 1024, 1024, MW3tH, MW3tL);
    init_summary_kernel<<<dim3(32768), dim3(256), 0, stream>>>(agg, sumH, sumL, sacc);
    tow_conv_all_kernel<<<dim3(32768), dim3(256), 0, stream>>>(towers, towAllH, towAllL);
  }

  const dim3 G(64, 8), B256(256);
  for (int k = 0; k < 16; ++k) {
    const _Float16* towH = towAllH + (size_t)k * 8192 * 64;
    const _Float16* towL = towAllL + (size_t)k * 8192 * 64;

    // K1m: x=[sum|tow] @ MW1^T -> m1 (split)
    gemm_split_kernel<<<G, B256, 0, stream>>>(sumH, sumL, 1024, towH, towL, 64,
                                              1024, 1088, MW1tH, MW1tL, Mb1, m1H, m1L, 1024);
    // K1h: x=[sum|tow] @ OW1^T -> h1 (fp16)
    gemm_h_kernel<<<G, B256, 0, stream>>>(sumH, 1024, towH, 64, 1024, 1088,
                                          OW1tH, Ob1, h1, 1024, nullptr, nullptr);
    // K2m: m1 @ MW2^T -> m2 (split)
    gemm_split_kernel<<<G, B256, 0, stream>>>(m1H, m1L, 1024, m1H, m1L, 1024,
                                              1024, 1024, MW2tH, MW2tL, Mb2, m2H, m2L, 1024);
    // K2h: h1 @ OW2^T -> fused relu+dot(OW3) into sacc (fp16)
    gemm_h_kernel<<<G, B256, 0, stream>>>(h1, 1024, h1, 1024, 1024, 1024,
                                          OW2tH, Ob2, nullptr, 1024, OW3, sacc);
    // K3: m2 @ MW3^T -> summary (split, in-place: K1m/K1h already consumed it)
    gemm_split_kernel<<<G, B256, 0, stream>>>(m2H, m2L, 1024, m2H, m2L, 1024,
                                              1024, 1024, MW3tH, MW3tL, Mb3, sumH, sumL, 1024);
    // pred + product accumulate + re-zero sacc
    pred_final_kernel<<<dim3(32), B256, 0, stream>>>(sacc, Ob3, out, k);
  }
}